// Round 1
// baseline (541.212 us; speedup 1.0000x reference)
//
#include <hip/hip_runtime.h>
#include <hip/hip_bf16.h>

#define M_DIM 8192
#define N_DIM 4096
#define K_DIM 4096
#define BM 128
#define BN 128
#define BK 32

typedef __bf16 bf16x8 __attribute__((ext_vector_type(8)));
typedef float  f32x4  __attribute__((ext_vector_type(4)));
typedef unsigned short u16x8 __attribute__((ext_vector_type(8)));

// async global->LDS, 16B per lane, dest = wave-uniform base + lane*16
#define ASYNC16(g, l)                                                          \
  __builtin_amdgcn_global_load_lds(                                            \
      (__attribute__((address_space(1))) void*)(g),                            \
      (__attribute__((address_space(3))) void*)(l), 16, 0, 0)

static __device__ __forceinline__ unsigned short f2bf(float f) {
  unsigned int u = __float_as_uint(f);
  u += 0x7fffu + ((u >> 16) & 1u);   // round-to-nearest-even
  return (unsigned short)(u >> 16);
}

// ---- x fp32 -> bf16, 8 elements/thread --------------------------------------
__global__ void sl_cvt_bf16(const float4* __restrict__ x4, u16x8* __restrict__ xb,
                            int n8) {
  int i = blockIdx.x * 256 + threadIdx.x;
  if (i >= n8) return;
  float4 a = x4[2 * i];
  float4 b = x4[2 * i + 1];
  u16x8 o;
  o[0] = f2bf(a.x); o[1] = f2bf(a.y); o[2] = f2bf(a.z); o[3] = f2bf(a.w);
  o[4] = f2bf(b.x); o[5] = f2bf(b.y); o[6] = f2bf(b.z); o[7] = f2bf(b.w);
  xb[i] = o;
}

// ---- COO scatter into dense bf16 W [N,K] ------------------------------------
__global__ void sl_scatter(const float* __restrict__ vals, const int* __restrict__ rows,
                           const int* __restrict__ cols, unsigned short* __restrict__ W,
                           int nnz) {
  int k = blockIdx.x * 256 + threadIdx.x;
  if (k >= nnz) return;
  W[(size_t)rows[k] * K_DIM + cols[k]] = f2bf(vals[k]);
}

// ---- bf16 MFMA GEMM: C[m][n] = sum_k A[m,k]*B[n,k] + bias[n] ----------------
// block 256 = 4 waves (2x2), wave computes 64x64 = 4x4 MFMA tiles of 16x16x32
__global__ __launch_bounds__(256) void sl_gemm_bias(
    const unsigned short* __restrict__ A,   // x bf16 [M,K]
    const unsigned short* __restrict__ B,   // W bf16 [N,K]
    const float* __restrict__ bias,
    float* __restrict__ C) {
  __shared__ __align__(16) unsigned short As[BM * BK]; // 8 KB, 64B/row
  __shared__ __align__(16) unsigned short Bs[BN * BK]; // 8 KB

  const int tid  = threadIdx.x;
  const int wave = tid >> 6;
  const int lane = tid & 63;
  const int m0 = blockIdx.x * BM;
  const int n0 = blockIdx.y * BN;

  // --- staging addressing: 16B chunks; chunk c covers row c>>2, cols (c&3)*8
  const int srow = tid >> 2;          // 0..63
  const int scol = (tid & 3) * 8;     // bf16 col within BK
  const unsigned short* gA0 = A + (size_t)(m0 + srow) * K_DIM + scol;
  const unsigned short* gA1 = gA0 + (size_t)64 * K_DIM;
  const unsigned short* gB0 = B + (size_t)(n0 + srow) * K_DIM + scol;
  const unsigned short* gB1 = gB0 + (size_t)64 * K_DIM;
  unsigned short* lA0 = As + (size_t)(wave * 64) * 8;        // wave-uniform bases
  unsigned short* lA1 = As + (size_t)(256 + wave * 64) * 8;
  unsigned short* lB0 = Bs + (size_t)(wave * 64) * 8;
  unsigned short* lB1 = Bs + (size_t)(256 + wave * 64) * 8;

  // --- fragment addressing
  const int wm   = (wave >> 1) * 64;
  const int wn   = (wave & 1) * 64;
  const int fm   = lane & 15;
  const int quad = lane >> 4;

  f32x4 acc[4][4] = {};

  for (int k0 = 0; k0 < K_DIM; k0 += BK) {
    ASYNC16(gA0, lA0);
    ASYNC16(gA1, lA1);
    ASYNC16(gB0, lB0);
    ASYNC16(gB1, lB1);
    gA0 += BK; gA1 += BK; gB0 += BK; gB1 += BK;
    __syncthreads();   // drains vmcnt -> LDS tiles complete

    bf16x8 af[4], bfr[4];
#pragma unroll
    for (int t = 0; t < 4; ++t) {
      af[t]  = *(const bf16x8*)(As + (size_t)(wm + t * 16 + fm) * BK + quad * 8);
      bfr[t] = *(const bf16x8*)(Bs + (size_t)(wn + t * 16 + fm) * BK + quad * 8);
    }
#pragma unroll
    for (int tm = 0; tm < 4; ++tm)
#pragma unroll
      for (int tn = 0; tn < 4; ++tn)
        acc[tm][tn] = __builtin_amdgcn_mfma_f32_16x16x32_bf16(
            af[tm], bfr[tn], acc[tm][tn], 0, 0, 0);
    __syncthreads();   // all waves done reading before next staging overwrites
  }

  // --- epilogue: D row = A-index (quad*4+reg), col = B-index (lane&15)
  float bv[4];
#pragma unroll
  for (int tn = 0; tn < 4; ++tn) bv[tn] = bias[n0 + wn + tn * 16 + fm];

#pragma unroll
  for (int tm = 0; tm < 4; ++tm) {
    const int mbase = m0 + wm + tm * 16 + quad * 4;
#pragma unroll
    for (int tn = 0; tn < 4; ++tn) {
      const int n = n0 + wn + tn * 16 + fm;
      float* p = C + (size_t)mbase * N_DIM + n;
#pragma unroll
      for (int r = 0; r < 4; ++r)
        p[(size_t)r * N_DIM] = acc[tm][tn][r] + bv[tn];
    }
  }
}

// ---- fallback (only if workspace too small): naive fp32 SpMM ----------------
__global__ void sl_naive(const float* __restrict__ x, const float* __restrict__ vals,
                         const int* __restrict__ rows, const int* __restrict__ cols,
                         const float* __restrict__ bias, float* __restrict__ out,
                         int nnz) {
  const int o = blockIdx.x;
  int l = 0, h = nnz;
  while (l < h) { int m = (l + h) >> 1; if (rows[m] < o) l = m + 1; else h = m; }
  const int s = l;
  h = nnz;
  while (l < h) { int m = (l + h) >> 1; if (rows[m] <= o) l = m + 1; else h = m; }
  const int e = l;
  const float bv = bias[o];
  for (int b = threadIdx.x; b < M_DIM; b += blockDim.x) {
    float acc = bv;
    const float* xb = x + (size_t)b * K_DIM;
    for (int k = s; k < e; ++k) acc += vals[k] * xb[cols[k]];
    out[(size_t)b * N_DIM + o] = acc;
  }
}

extern "C" void kernel_launch(void* const* d_in, const int* in_sizes, int n_in,
                              void* d_out, int out_size, void* d_ws, size_t ws_size,
                              hipStream_t stream) {
  const float* x    = (const float*)d_in[0];
  const float* vals = (const float*)d_in[1];
  const int*   rows = (const int*)d_in[2];
  const int*   cols = (const int*)d_in[3];
  const float* bias = (const float*)d_in[4];
  float* out = (float*)d_out;
  const int nnz = in_sizes[1];

  const size_t xb_bytes = (size_t)M_DIM * K_DIM * 2;  // 64 MiB
  const size_t w_bytes  = (size_t)N_DIM * K_DIM * 2;  // 32 MiB

  if (ws_size >= xb_bytes + w_bytes) {
    unsigned short* xb = (unsigned short*)d_ws;
    unsigned short* W  = (unsigned short*)((char*)d_ws + xb_bytes);

    hipMemsetAsync(W, 0, w_bytes, stream);
    const int n8 = (M_DIM * K_DIM) / 8;
    sl_cvt_bf16<<<(n8 + 255) / 256, 256, 0, stream>>>((const float4*)x, (u16x8*)xb, n8);
    sl_scatter<<<(nnz + 255) / 256, 256, 0, stream>>>(vals, rows, cols, W, nnz);
    sl_gemm_bias<<<dim3(M_DIM / BM, N_DIM / BN), 256, 0, stream>>>(xb, W, bias, out);
  } else {
    sl_naive<<<N_DIM, 256, 0, stream>>>(x, vals, rows, cols, bias, out, nnz);
  }
}